// Round 7
// baseline (332.729 us; speedup 1.0000x reference)
//
#include <hip/hip_runtime.h>

// Split kernels (fusion disproven R3/R5; multi-var changes of R6 reverted).
// K1 conv: R4 body (1 batch-pair per wave, DPP reductions, packed fp32) inside
//   a grid-stride 4-iteration loop (2048 blocks x 4 waves = 8192 waves, each
//   wave does pairs {wid, wid+8192, wid+16384, wid+24576}) with 1-deep x
//   prefetch. Loop-invariant weight s_loads amortize over 4 pairs.
// K2 mlp: exact R4 shape: 256-thread blocks, wave p = out-slice [16p,16p+16),
//   lane = batch, LDS stride-65 activation exchange, packed fp32.

typedef float v2f __attribute__((ext_vector_type(2)));
__device__ __forceinline__ v2f fma2(v2f a, v2f b, v2f c) {
  return __builtin_elementwise_fma(a, b, c);
}
__device__ __forceinline__ v2f ld2(const float* p) { return *(const v2f*)p; }

__device__ __forceinline__ float fast_tanh(float v) {
  // no clamp needed: rcp(inf)=0 saturates to +/-1 correctly
  float e = exp2f(v * 2.8853900817779268f);          // e^(2v)
  return 1.f - 2.f * __builtin_amdgcn_rcpf(e + 1.f); // (e-1)/(e+1)
}

template<int CTRL, int RMASK>
__device__ __forceinline__ float dpp0(float v) {
  return __int_as_float(__builtin_amdgcn_update_dpp(
      0, __float_as_int(v), CTRL, RMASK, 0xf, true));
}
// 32-lane reductions (per half-wave), result valid in lanes 31/63. id = 0.
__device__ __forceinline__ float red_max32(float t) {  // requires t >= 0
  t = fmaxf(t, dpp0<0x111, 0xf>(t)); // row_shr:1
  t = fmaxf(t, dpp0<0x112, 0xf>(t)); // row_shr:2
  t = fmaxf(t, dpp0<0x114, 0xf>(t)); // row_shr:4
  t = fmaxf(t, dpp0<0x118, 0xf>(t)); // row_shr:8
  t = fmaxf(t, dpp0<0x142, 0xa>(t)); // row_bcast:15 -> rows 1,3
  return t;
}
__device__ __forceinline__ float red_sum32(float t) {
  t += dpp0<0x111, 0xf>(t);
  t += dpp0<0x112, 0xf>(t);
  t += dpp0<0x114, 0xf>(t);
  t += dpp0<0x118, 0xf>(t);
  t += dpp0<0x142, 0xa>(t);
  return t;
}
// broadcast lane31 of each 32-lane group (1 DS op)
__device__ __forceinline__ float bcast31(float v) {
  return __int_as_float(__builtin_amdgcn_ds_swizzle(__float_as_int(v), 0x03E0));
}

#define NWAVES 8192  // grid 2048 x 4 waves; 32768 pairs / 8192 = 4 iters

// ===================== K1: conv1 + conv2 + per-batch pooling ================
__global__ __launch_bounds__(256, 4) void conv_kernel(
    const float* __restrict__ x,
    const float* __restrict__ Wp1, const float* __restrict__ bp1,
    const float* __restrict__ Ws1, const float* __restrict__ Wn1,
    const float* __restrict__ bc1,
    const float* __restrict__ Wp2, const float* __restrict__ bp2,
    float* __restrict__ res) {
  const int lane = threadIdx.x & 63;
  const int wid  = blockIdx.x * 4 + (threadIdx.x >> 6); // 0..8191
  const int nl = lane & 31, s = lane >> 5;
  const int node = 31 - nl;           // node0 <-> lane31/63
  const bool isn0 = (nl == 31);

  // pair for iter i: wid + NWAVES*i ; batch = pair*2+s
  const size_t xstep = (size_t)NWAVES * 2 * 32 * 16;  // floats between iters
  const float* xb = x + (((size_t)(wid * 2 + s)) * 32 + node) * 16;
  float4 c0, c1, c2, c3;
  { const float4* xp = (const float4*)xb; c0 = xp[0]; c1 = xp[1]; c2 = xp[2]; c3 = xp[3]; }

  #pragma unroll 1
  for (int it = 0; it < 4; ++it) {
    float4 nx0, nx1, nx2, nx3;
    if (it < 3) {  // 1-deep prefetch of next iter's rows
      const float4* xp = (const float4*)(xb + xstep * (it + 1));
      nx0 = xp[0]; nx1 = xp[1]; nx2 = xp[2]; nx3 = xp[3];
    }
    float xr[16] = {c0.x,c0.y,c0.z,c0.w, c1.x,c1.y,c1.z,c1.w,
                    c2.x,c2.y,c2.z,c2.w, c3.x,c3.y,c3.z,c3.w};

    // conv1: m = relu(x@Wp1+bp1), sp = x@Ws1 + bc1  (packed fp32)
    v2f mv[4], sv[4];
    #pragma unroll
    for (int i = 0; i < 4; i++) { mv[i] = ld2(bp1 + 2*i); sv[i] = ld2(bc1 + 2*i); }
    #pragma unroll
    for (int f = 0; f < 16; f++) {
      v2f xv = {xr[f], xr[f]};
      #pragma unroll
      for (int i = 0; i < 4; i++) {
        mv[i] = fma2(xv, ld2(Wp1 + f*8 + 2*i), mv[i]);
        sv[i] = fma2(xv, ld2(Ws1 + f*8 + 2*i), sv[i]);
      }
    }
    float m[8];
    #pragma unroll
    for (int i = 0; i < 4; i++) {
      m[2*i]   = fmaxf(mv[i].x, 0.f);
      m[2*i+1] = fmaxf(mv[i].y, 0.f);
    }

    // star scatter-max: node0 <- max over leaves; leaves <- m[node0]
    float agg[8];
    #pragma unroll
    for (int g = 0; g < 8; g++) {
      float t = isn0 ? 0.f : m[g];
      t = red_max32(t);
      float b0v = bcast31(m[g]);
      agg[g] = isn0 ? t : b0v;
    }
    #pragma unroll
    for (int jj = 0; jj < 8; jj++) {
      v2f av = {agg[jj], agg[jj]};
      #pragma unroll
      for (int i = 0; i < 4; i++) sv[i] = fma2(av, ld2(Wn1 + jj*8 + 2*i), sv[i]);
    }
    float h[8];
    #pragma unroll
    for (int i = 0; i < 4; i++) {
      h[2*i]   = fast_tanh(sv[i].x);
      h[2*i+1] = fast_tanh(sv[i].y);
    }

    // conv2 pool-proj: m2 = relu(h@Wp2+bp2)
    v2f m2v[4];
    #pragma unroll
    for (int i = 0; i < 4; i++) m2v[i] = ld2(bp2 + 2*i);
    #pragma unroll
    for (int jj = 0; jj < 8; jj++) {
      v2f hv = {h[jj], h[jj]};
      #pragma unroll
      for (int i = 0; i < 4; i++) m2v[i] = fma2(hv, ld2(Wp2 + jj*8 + 2*i), m2v[i]);
    }
    float m2[8];
    #pragma unroll
    for (int i = 0; i < 4; i++) {
      m2[2*i]   = fmaxf(m2v[i].x, 0.f);
      m2[2*i+1] = fmaxf(m2v[i].y, 0.f);
    }

    // per-batch reductions; valid at lanes 31/63 (= node0 = the storer)
    float outv[16];
    #pragma unroll
    for (int g = 0; g < 8; g++) outv[g] = red_sum32(h[g]);
    #pragma unroll
    for (int g = 0; g < 8; g++) {
      float t = isn0 ? 0.f : m2[g];
      t = red_max32(t);
      outv[8+g] = fmaf(31.f, m2[g], t);  // + 31 * m2[node0] (lane31 holds it)
    }
    if (isn0) {
      const int b = (wid + NWAVES * it) * 2 + s;
      float4* rp = (float4*)(res + (size_t)b * 16);
      rp[0] = make_float4(outv[0],  outv[1],  outv[2],  outv[3]);
      rp[1] = make_float4(outv[4],  outv[5],  outv[6],  outv[7]);
      rp[2] = make_float4(outv[8],  outv[9],  outv[10], outv[11]);
      rp[3] = make_float4(outv[12], outv[13], outv[14], outv[15]);
    }
    if (it < 3) { c0 = nx0; c1 = nx1; c2 = nx2; c3 = nx3; }
  }
}

// ===================== K2: pooled fold + 4-layer MLP (R4-proven) ============
#define HSTR 65  // LDS row stride: odd -> conflict-free scalar reads
__global__ __launch_bounds__(256, 3) void mlp_kernel(
    const float* __restrict__ res, const float* __restrict__ obs,
    const float* __restrict__ Ws2, const float* __restrict__ Wn2,
    const float* __restrict__ bc2,
    const float* __restrict__ W1, const float* __restrict__ bf1,
    const float* __restrict__ W2, const float* __restrict__ bf2,
    const float* __restrict__ W3, const float* __restrict__ bf3,
    const float* __restrict__ W4, const float* __restrict__ bf4,
    float* __restrict__ out) {
  __shared__ float hx[64 * HSTR];
  const int tid  = threadIdx.x;
  const int lane = tid & 63;                                  // batch in block
  const int p    = __builtin_amdgcn_readfirstlane(tid >> 6);  // wave 0..3
  const int b    = blockIdx.x * 64 + lane;
  const int ob0  = p * 16;

  const float4* rp = (const float4*)(res + (size_t)b * 16);
  float4 r0 = rp[0], r1 = rp[1], r2 = rp[2], r3 = rp[3];
  const float4* op = (const float4*)(obs + (size_t)b * 16);
  float4 o0 = op[0], o1 = op[1], o2 = op[2], o3 = op[3];
  float rm[8] = {r0.x,r0.y,r0.z,r0.w, r1.x,r1.y,r1.z,r1.w};
  float ag[8] = {r2.x,r2.y,r2.z,r2.w, r3.x,r3.y,r3.z,r3.w};
  float ob[16] = {o0.x,o0.y,o0.z,o0.w, o1.x,o1.y,o1.z,o1.w,
                  o2.x,o2.y,o2.z,o2.w, o3.x,o3.y,o3.z,o3.w};

  // pooled = (sumh@Ws2 + sumagg2@Wn2)/32 + bc2
  v2f pv[4];
  #pragma unroll
  for (int i = 0; i < 4; i++) pv[i] = (v2f){0.f, 0.f};
  #pragma unroll
  for (int jj = 0; jj < 8; jj++) {
    v2f rv = {rm[jj], rm[jj]}, av = {ag[jj], ag[jj]};
    #pragma unroll
    for (int i = 0; i < 4; i++) {
      pv[i] = fma2(rv, ld2(Ws2 + jj*8 + 2*i), pv[i]);
      pv[i] = fma2(av, ld2(Wn2 + jj*8 + 2*i), pv[i]);
    }
  }
  float pooled[8];
  #pragma unroll
  for (int i = 0; i < 4; i++) {
    pooled[2*i]   = fmaf(pv[i].x, 1.f/32.f, bc2[2*i]);
    pooled[2*i+1] = fmaf(pv[i].y, 1.f/32.f, bc2[2*i+1]);
  }

  v2f acc[8];
  // ---- layer 1: [pooled | obs] @ W1 + bf1, slice [ob0, ob0+16) ----
  #pragma unroll
  for (int i = 0; i < 8; i++) acc[i] = ld2(bf1 + ob0 + 2*i);
  #pragma unroll
  for (int jj = 0; jj < 8; jj++) {
    v2f sj = {pooled[jj], pooled[jj]};
    #pragma unroll
    for (int i = 0; i < 8; i++) acc[i] = fma2(sj, ld2(W1 + jj*64 + ob0 + 2*i), acc[i]);
  }
  #pragma unroll
  for (int jj = 0; jj < 16; jj++) {
    v2f sj = {ob[jj], ob[jj]};
    #pragma unroll
    for (int i = 0; i < 8; i++) acc[i] = fma2(sj, ld2(W1 + (8+jj)*64 + ob0 + 2*i), acc[i]);
  }
  #pragma unroll
  for (int i = 0; i < 8; i++) {
    hx[lane*HSTR + ob0 + 2*i]   = fmaxf(acc[i].x, 0.f);
    hx[lane*HSTR + ob0 + 2*i+1] = fmaxf(acc[i].y, 0.f);
  }
  __syncthreads();
  float h[64];
  #pragma unroll
  for (int k = 0; k < 64; k++) h[k] = hx[lane*HSTR + k];
  __syncthreads();

  // ---- layer 2 ----
  #pragma unroll
  for (int i = 0; i < 8; i++) acc[i] = ld2(bf2 + ob0 + 2*i);
  #pragma unroll
  for (int k = 0; k < 64; k++) {
    v2f hk = {h[k], h[k]};
    #pragma unroll
    for (int i = 0; i < 8; i++) acc[i] = fma2(hk, ld2(W2 + k*64 + ob0 + 2*i), acc[i]);
  }
  #pragma unroll
  for (int i = 0; i < 8; i++) {
    hx[lane*HSTR + ob0 + 2*i]   = fmaxf(acc[i].x, 0.f);
    hx[lane*HSTR + ob0 + 2*i+1] = fmaxf(acc[i].y, 0.f);
  }
  __syncthreads();
  #pragma unroll
  for (int k = 0; k < 64; k++) h[k] = hx[lane*HSTR + k];
  __syncthreads();

  // ---- layer 3 ----
  #pragma unroll
  for (int i = 0; i < 8; i++) acc[i] = ld2(bf3 + ob0 + 2*i);
  #pragma unroll
  for (int k = 0; k < 64; k++) {
    v2f hk = {h[k], h[k]};
    #pragma unroll
    for (int i = 0; i < 8; i++) acc[i] = fma2(hk, ld2(W3 + k*64 + ob0 + 2*i), acc[i]);
  }
  #pragma unroll
  for (int i = 0; i < 8; i++) {
    hx[lane*HSTR + ob0 + 2*i]   = fmaxf(acc[i].x, 0.f);
    hx[lane*HSTR + ob0 + 2*i+1] = fmaxf(acc[i].y, 0.f);
  }
  __syncthreads();

  // ---- layer 4 + tanh (wave 0 only) ----
  if (p == 0) {
    #pragma unroll
    for (int k = 0; k < 64; k++) h[k] = hx[lane*HSTR + k];
    v2f o4a = ld2(bf4), o4b = ld2(bf4 + 2);
    #pragma unroll
    for (int k = 0; k < 64; k++) {
      v2f hk = {h[k], h[k]};
      o4a = fma2(hk, ld2(W4 + k*4),     o4a);
      o4b = fma2(hk, ld2(W4 + k*4 + 2), o4b);
    }
    ((float4*)out)[b] = make_float4(fast_tanh(o4a.x), fast_tanh(o4a.y),
                                    fast_tanh(o4b.x), fast_tanh(o4b.y));
  }
}

extern "C" void kernel_launch(void* const* d_in, const int* in_sizes, int n_in,
                              void* d_out, int out_size, void* d_ws, size_t ws_size,
                              hipStream_t stream) {
  const float* x   = (const float*)d_in[0];
  const float* obs = (const float*)d_in[1];
  // d_in[2..4] = src/dst/node_seg: fixed star graph, exploited structurally
  const float* Wp1 = (const float*)d_in[5];
  const float* bp1 = (const float*)d_in[6];
  const float* Ws1 = (const float*)d_in[7];
  const float* Wn1 = (const float*)d_in[8];
  const float* bc1 = (const float*)d_in[9];
  const float* Wp2 = (const float*)d_in[10];
  const float* bp2 = (const float*)d_in[11];
  const float* Ws2 = (const float*)d_in[12];
  const float* Wn2 = (const float*)d_in[13];
  const float* bc2 = (const float*)d_in[14];
  const float* W1  = (const float*)d_in[15];
  const float* bf1 = (const float*)d_in[16];
  const float* W2  = (const float*)d_in[17];
  const float* bf2 = (const float*)d_in[18];
  const float* W3  = (const float*)d_in[19];
  const float* bf3 = (const float*)d_in[20];
  const float* W4  = (const float*)d_in[21];
  const float* bf4 = (const float*)d_in[22];
  float* res = (float*)d_ws;  // [65536][16] floats = 4 MB
  float* out = (float*)d_out;

  hipLaunchKernelGGL(conv_kernel, dim3(2048), dim3(256), 0, stream,
                     x, Wp1, bp1, Ws1, Wn1, bc1, Wp2, bp2, res);
  hipLaunchKernelGGL(mlp_kernel, dim3(1024), dim3(256), 0, stream,
                     res, obs, Ws2, Wn2, bc2, W1, bf1, W2, bf2, W3, bf3, W4, bf4, out);
}

// Round 8
// 282.121 us; speedup vs baseline: 1.1794x; 1.1794x over previous
//
#include <hip/hip_runtime.h>

// K1 conv: EXACT R4 shape (best measured): 8192 blocks x 256, 1 batch-pair per
//   wave, straight-line, DPP reductions, packed fp32, node0 <-> lane31/63.
//   (Looped/multi-pair variants falsified twice: R6 straight-line-2x, R7
//   grid-stride-4x both regressed. Max wave count + shortest body wins.)
// K2 mlp (experiment): 128 batches per block (2 per lane) to halve the
//   per-batch scalar weight stream. Activations live in LDS and are re-read
//   per-k (ds_read_b32 broadcast pattern, stride-odd = conflict-free);
//   in-place hx update with read -> barrier -> write ordering.

typedef float v2f __attribute__((ext_vector_type(2)));
__device__ __forceinline__ v2f fma2(v2f a, v2f b, v2f c) {
  return __builtin_elementwise_fma(a, b, c);
}
__device__ __forceinline__ v2f ld2(const float* p) { return *(const v2f*)p; }

__device__ __forceinline__ float fast_tanh(float v) {
  // no clamp needed: rcp(inf)=0 saturates to +/-1 correctly
  float e = exp2f(v * 2.8853900817779268f);          // e^(2v)
  return 1.f - 2.f * __builtin_amdgcn_rcpf(e + 1.f); // (e-1)/(e+1)
}

template<int CTRL, int RMASK>
__device__ __forceinline__ float dpp0(float v) {
  return __int_as_float(__builtin_amdgcn_update_dpp(
      0, __float_as_int(v), CTRL, RMASK, 0xf, true));
}
// 32-lane reductions (per half-wave), result valid in lanes 31/63. id = 0.
__device__ __forceinline__ float red_max32(float t) {  // requires t >= 0
  t = fmaxf(t, dpp0<0x111, 0xf>(t)); // row_shr:1
  t = fmaxf(t, dpp0<0x112, 0xf>(t)); // row_shr:2
  t = fmaxf(t, dpp0<0x114, 0xf>(t)); // row_shr:4
  t = fmaxf(t, dpp0<0x118, 0xf>(t)); // row_shr:8
  t = fmaxf(t, dpp0<0x142, 0xa>(t)); // row_bcast:15 -> rows 1,3
  return t;
}
__device__ __forceinline__ float red_sum32(float t) {
  t += dpp0<0x111, 0xf>(t);
  t += dpp0<0x112, 0xf>(t);
  t += dpp0<0x114, 0xf>(t);
  t += dpp0<0x118, 0xf>(t);
  t += dpp0<0x142, 0xa>(t);
  return t;
}
// broadcast lane31 of each 32-lane group (1 DS op)
__device__ __forceinline__ float bcast31(float v) {
  return __int_as_float(__builtin_amdgcn_ds_swizzle(__float_as_int(v), 0x03E0));
}

// ===================== K1: conv1 + conv2 + per-batch pooling (R4) ===========
__global__ __launch_bounds__(256, 4) void conv_kernel(
    const float* __restrict__ x,
    const float* __restrict__ Wp1, const float* __restrict__ bp1,
    const float* __restrict__ Ws1, const float* __restrict__ Wn1,
    const float* __restrict__ bc1,
    const float* __restrict__ Wp2, const float* __restrict__ bp2,
    float* __restrict__ res) {
  const int lane = threadIdx.x & 63;
  const int pair = blockIdx.x * 4 + (threadIdx.x >> 6);
  const int nl = lane & 31, s = lane >> 5;
  const int node = 31 - nl;           // node0 <-> lane31/63
  const bool isn0 = (nl == 31);
  const int b = pair * 2 + s;

  const float4* xp = (const float4*)(x + ((size_t)b * 32 + node) * 16);
  float4 a0 = xp[0], a1 = xp[1], a2 = xp[2], a3 = xp[3];
  float xr[16] = {a0.x,a0.y,a0.z,a0.w, a1.x,a1.y,a1.z,a1.w,
                  a2.x,a2.y,a2.z,a2.w, a3.x,a3.y,a3.z,a3.w};

  // conv1: m = relu(x@Wp1+bp1), sp = x@Ws1 + bc1  (packed fp32)
  v2f mv[4], sv[4];
  #pragma unroll
  for (int i = 0; i < 4; i++) { mv[i] = ld2(bp1 + 2*i); sv[i] = ld2(bc1 + 2*i); }
  #pragma unroll
  for (int f = 0; f < 16; f++) {
    v2f xv = {xr[f], xr[f]};
    #pragma unroll
    for (int i = 0; i < 4; i++) {
      mv[i] = fma2(xv, ld2(Wp1 + f*8 + 2*i), mv[i]);
      sv[i] = fma2(xv, ld2(Ws1 + f*8 + 2*i), sv[i]);
    }
  }
  float m[8];
  #pragma unroll
  for (int i = 0; i < 4; i++) {
    m[2*i]   = fmaxf(mv[i].x, 0.f);
    m[2*i+1] = fmaxf(mv[i].y, 0.f);
  }

  // star scatter-max: node0 <- max over leaves; leaves <- m[node0]
  float agg[8];
  #pragma unroll
  for (int g = 0; g < 8; g++) {
    float t = isn0 ? 0.f : m[g];
    t = red_max32(t);
    float b0v = bcast31(m[g]);
    agg[g] = isn0 ? t : b0v;
  }
  #pragma unroll
  for (int jj = 0; jj < 8; jj++) {
    v2f av = {agg[jj], agg[jj]};
    #pragma unroll
    for (int i = 0; i < 4; i++) sv[i] = fma2(av, ld2(Wn1 + jj*8 + 2*i), sv[i]);
  }
  float h[8];
  #pragma unroll
  for (int i = 0; i < 4; i++) {
    h[2*i]   = fast_tanh(sv[i].x);
    h[2*i+1] = fast_tanh(sv[i].y);
  }

  // conv2 pool-proj: m2 = relu(h@Wp2+bp2)
  v2f m2v[4];
  #pragma unroll
  for (int i = 0; i < 4; i++) m2v[i] = ld2(bp2 + 2*i);
  #pragma unroll
  for (int jj = 0; jj < 8; jj++) {
    v2f hv = {h[jj], h[jj]};
    #pragma unroll
    for (int i = 0; i < 4; i++) m2v[i] = fma2(hv, ld2(Wp2 + jj*8 + 2*i), m2v[i]);
  }
  float m2[8];
  #pragma unroll
  for (int i = 0; i < 4; i++) {
    m2[2*i]   = fmaxf(m2v[i].x, 0.f);
    m2[2*i+1] = fmaxf(m2v[i].y, 0.f);
  }

  // per-batch reductions; valid at lanes 31/63 (= node0 = the storer)
  float outv[16];
  #pragma unroll
  for (int g = 0; g < 8; g++) outv[g] = red_sum32(h[g]);
  #pragma unroll
  for (int g = 0; g < 8; g++) {
    float t = isn0 ? 0.f : m2[g];
    t = red_max32(t);
    outv[8+g] = fmaf(31.f, m2[g], t);  // + 31 * m2[node0] (lane31 holds it)
  }
  if (isn0) {
    float4* rp = (float4*)(res + (size_t)b * 16);
    rp[0] = make_float4(outv[0],  outv[1],  outv[2],  outv[3]);
    rp[1] = make_float4(outv[4],  outv[5],  outv[6],  outv[7]);
    rp[2] = make_float4(outv[8],  outv[9],  outv[10], outv[11]);
    rp[3] = make_float4(outv[12], outv[13], outv[14], outv[15]);
  }
}

// ===================== K2: MLP, 128 batches/block ===========================
#define H0S 25  // h0 row stride (24 inputs + pad), odd -> conflict-free
#define HXS 65  // hx row stride, odd -> conflict-free
__global__ __launch_bounds__(256, 3) void mlp_kernel(
    const float* __restrict__ res, const float* __restrict__ obs,
    const float* __restrict__ Ws2, const float* __restrict__ Wn2,
    const float* __restrict__ bc2,
    const float* __restrict__ W1, const float* __restrict__ bf1,
    const float* __restrict__ W2, const float* __restrict__ bf2,
    const float* __restrict__ W3, const float* __restrict__ bf3,
    const float* __restrict__ W4, const float* __restrict__ bf4,
    float* __restrict__ out) {
  __shared__ float h0[128 * H0S];  // [pooled(8) | obs(16)] per batch
  __shared__ float hx[128 * HXS];  // hidden activations, updated in place
  const int tid  = threadIdx.x;
  const int lane = tid & 63;
  const int p    = __builtin_amdgcn_readfirstlane(tid >> 6);  // slice wave 0..3
  const int ob0  = p * 16;
  const int bbase = blockIdx.x * 128;

  // ---- phase 0: threads 0..127 build h0 rows (pooled fold + obs copy) ----
  if (tid < 128) {
    const float4* rp = (const float4*)(res + (size_t)(bbase + tid) * 16);
    float4 r0 = rp[0], r1 = rp[1], r2 = rp[2], r3 = rp[3];
    const float4* op = (const float4*)(obs + (size_t)(bbase + tid) * 16);
    float4 o0 = op[0], o1 = op[1], o2 = op[2], o3 = op[3];
    float rm[8] = {r0.x,r0.y,r0.z,r0.w, r1.x,r1.y,r1.z,r1.w};
    float ag[8] = {r2.x,r2.y,r2.z,r2.w, r3.x,r3.y,r3.z,r3.w};
    v2f pv[4];
    #pragma unroll
    for (int i = 0; i < 4; i++) pv[i] = (v2f){0.f, 0.f};
    #pragma unroll
    for (int j = 0; j < 8; j++) {
      v2f rv = {rm[j], rm[j]}, av = {ag[j], ag[j]};
      #pragma unroll
      for (int i = 0; i < 4; i++) {
        pv[i] = fma2(rv, ld2(Ws2 + j*8 + 2*i), pv[i]);
        pv[i] = fma2(av, ld2(Wn2 + j*8 + 2*i), pv[i]);
      }
    }
    float* hr = h0 + tid * H0S;
    #pragma unroll
    for (int i = 0; i < 4; i++) {
      hr[2*i]   = fmaf(pv[i].x, 1.f/32.f, bc2[2*i]);
      hr[2*i+1] = fmaf(pv[i].y, 1.f/32.f, bc2[2*i+1]);
    }
    hr[8]=o0.x;  hr[9]=o0.y;  hr[10]=o0.z; hr[11]=o0.w;
    hr[12]=o1.x; hr[13]=o1.y; hr[14]=o1.z; hr[15]=o1.w;
    hr[16]=o2.x; hr[17]=o2.y; hr[18]=o2.z; hr[19]=o2.w;
    hr[20]=o3.x; hr[21]=o3.y; hr[22]=o3.z; hr[23]=o3.w;
  }
  __syncthreads();

  const float* h0a = h0 + lane * H0S;
  const float* h0b = h0 + (64 + lane) * H0S;
  float* hxa = hx + lane * HXS;
  float* hxb = hx + (64 + lane) * HXS;

  v2f acc0[8], acc1[8];
  // ---- layer 1: 24 inputs -> slice [ob0, ob0+16), two batches per lane ----
  #pragma unroll
  for (int i = 0; i < 8; i++) { acc0[i] = ld2(bf1 + ob0 + 2*i); acc1[i] = acc0[i]; }
  #pragma unroll
  for (int k = 0; k < 24; k++) {
    v2f a0 = {h0a[k], h0a[k]}, a1 = {h0b[k], h0b[k]};
    #pragma unroll
    for (int i = 0; i < 8; i++) {
      v2f w = ld2(W1 + k*64 + ob0 + 2*i);
      acc0[i] = fma2(a0, w, acc0[i]);
      acc1[i] = fma2(a1, w, acc1[i]);
    }
  }
  // hx not yet read by anyone: write directly, then publish
  #pragma unroll
  for (int i = 0; i < 8; i++) {
    hxa[ob0 + 2*i]   = fmaxf(acc0[i].x, 0.f);
    hxa[ob0 + 2*i+1] = fmaxf(acc0[i].y, 0.f);
    hxb[ob0 + 2*i]   = fmaxf(acc1[i].x, 0.f);
    hxb[ob0 + 2*i+1] = fmaxf(acc1[i].y, 0.f);
  }
  __syncthreads();

  // ---- layer 2 (in-place: read all k, barrier, write) ----
  #pragma unroll
  for (int i = 0; i < 8; i++) { acc0[i] = ld2(bf2 + ob0 + 2*i); acc1[i] = acc0[i]; }
  #pragma unroll
  for (int k = 0; k < 64; k++) {
    v2f a0 = {hxa[k], hxa[k]}, a1 = {hxb[k], hxb[k]};
    #pragma unroll
    for (int i = 0; i < 8; i++) {
      v2f w = ld2(W2 + k*64 + ob0 + 2*i);
      acc0[i] = fma2(a0, w, acc0[i]);
      acc1[i] = fma2(a1, w, acc1[i]);
    }
  }
  __syncthreads();
  #pragma unroll
  for (int i = 0; i < 8; i++) {
    hxa[ob0 + 2*i]   = fmaxf(acc0[i].x, 0.f);
    hxa[ob0 + 2*i+1] = fmaxf(acc0[i].y, 0.f);
    hxb[ob0 + 2*i]   = fmaxf(acc1[i].x, 0.f);
    hxb[ob0 + 2*i+1] = fmaxf(acc1[i].y, 0.f);
  }
  __syncthreads();

  // ---- layer 3 ----
  #pragma unroll
  for (int i = 0; i < 8; i++) { acc0[i] = ld2(bf3 + ob0 + 2*i); acc1[i] = acc0[i]; }
  #pragma unroll
  for (int k = 0; k < 64; k++) {
    v2f a0 = {hxa[k], hxa[k]}, a1 = {hxb[k], hxb[k]};
    #pragma unroll
    for (int i = 0; i < 8; i++) {
      v2f w = ld2(W3 + k*64 + ob0 + 2*i);
      acc0[i] = fma2(a0, w, acc0[i]);
      acc1[i] = fma2(a1, w, acc1[i]);
    }
  }
  __syncthreads();
  #pragma unroll
  for (int i = 0; i < 8; i++) {
    hxa[ob0 + 2*i]   = fmaxf(acc0[i].x, 0.f);
    hxa[ob0 + 2*i+1] = fmaxf(acc0[i].y, 0.f);
    hxb[ob0 + 2*i]   = fmaxf(acc1[i].x, 0.f);
    hxb[ob0 + 2*i+1] = fmaxf(acc1[i].y, 0.f);
  }
  __syncthreads();

  // ---- layer 4 + tanh (wave 0 only, both batches) ----
  if (p == 0) {
    v2f qa0 = ld2(bf4), qb0 = ld2(bf4 + 2);
    v2f qa1 = qa0, qb1 = qb0;
    #pragma unroll
    for (int k = 0; k < 64; k++) {
      v2f a0 = {hxa[k], hxa[k]}, a1 = {hxb[k], hxb[k]};
      v2f w0 = ld2(W4 + k*4), w1 = ld2(W4 + k*4 + 2);
      qa0 = fma2(a0, w0, qa0); qb0 = fma2(a0, w1, qb0);
      qa1 = fma2(a1, w0, qa1); qb1 = fma2(a1, w1, qb1);
    }
    ((float4*)out)[bbase + lane] =
        make_float4(fast_tanh(qa0.x), fast_tanh(qa0.y),
                    fast_tanh(qb0.x), fast_tanh(qb0.y));
    ((float4*)out)[bbase + 64 + lane] =
        make_float4(fast_tanh(qa1.x), fast_tanh(qa1.y),
                    fast_tanh(qb1.x), fast_tanh(qb1.y));
  }
}

extern "C" void kernel_launch(void* const* d_in, const int* in_sizes, int n_in,
                              void* d_out, int out_size, void* d_ws, size_t ws_size,
                              hipStream_t stream) {
  const float* x   = (const float*)d_in[0];
  const float* obs = (const float*)d_in[1];
  // d_in[2..4] = src/dst/node_seg: fixed star graph, exploited structurally
  const float* Wp1 = (const float*)d_in[5];
  const float* bp1 = (const float*)d_in[6];
  const float* Ws1 = (const float*)d_in[7];
  const float* Wn1 = (const float*)d_in[8];
  const float* bc1 = (const float*)d_in[9];
  const float* Wp2 = (const float*)d_in[10];
  const float* bp2 = (const float*)d_in[11];
  const float* Ws2 = (const float*)d_in[12];
  const float* Wn2 = (const float*)d_in[13];
  const float* bc2 = (const float*)d_in[14];
  const float* W1  = (const float*)d_in[15];
  const float* bf1 = (const float*)d_in[16];
  const float* W2  = (const float*)d_in[17];
  const float* bf2 = (const float*)d_in[18];
  const float* W3  = (const float*)d_in[19];
  const float* bf3 = (const float*)d_in[20];
  const float* W4  = (const float*)d_in[21];
  const float* bf4 = (const float*)d_in[22];
  float* res = (float*)d_ws;  // [65536][16] floats = 4 MB
  float* out = (float*)d_out;

  hipLaunchKernelGGL(conv_kernel, dim3(8192), dim3(256), 0, stream,
                     x, Wp1, bp1, Ws1, Wn1, bc1, Wp2, bp2, res);
  hipLaunchKernelGGL(mlp_kernel, dim3(512), dim3(256), 0, stream,
                     res, obs, Ws2, Wn2, bc2, W1, bf1, W2, bf2, W3, bf3, W4, bf4, out);
}